// Round 18
// baseline (187.476 us; speedup 1.0000x reference)
//
#include <hip/hip_runtime.h>
#include <hip/hip_bf16.h>
#include <hip/hip_fp16.h>

static constexpr int NN = 1000000;   // nodes
static constexpr int NE = 5000000;   // edges
static constexpr int NG = 4096;      // graphs
static constexpr int BIN_SH = 8;                      // 256 nodes per bin
static constexpr int BIN_SZ = 1 << BIN_SH;            // 256
static constexpr int NB = (NN + BIN_SZ - 1) >> BIN_SH;   // 3907 (last bin = 64 nodes, %64==0)
static constexpr int CAP_SH = 11;                     // 2048 edge slots per bin
static constexpr int CAP = 1 << CAP_SH;
static constexpr int EPB = 16384;                     // edges per block for the scatter pass
static constexpr int EPW = EPB / 1024;                // 16 edges per thread in scatter
static constexpr int BIN_BLOCKS = (NE + EPB - 1) / EPB;  // 306 (1024-thread blocks)
static constexpr int CHUNK = 512;                     // edges per LDS chunk (18 KB -> 8 blocks/CU)
static constexpr float KEXP = 2.8853900817779268f;    // 2*log2(e): tanh(v)=1-2/(2^(K v)+1)

__device__ __forceinline__ float exp2_fast(float x) {
#if __has_builtin(__builtin_amdgcn_exp2f)
    return __builtin_amdgcn_exp2f(x);
#else
    return exp2f(x);
#endif
}

// tanh from pre-scaled argument s = KEXP * v: tanh(v) = 1 - 2/(2^s + 1).
// Exact at extremes (2^s=inf -> 1, 2^s=0 -> -1); no clamp needed.
__device__ __forceinline__ float tanh_scaled(float s) {
    float e = exp2_fast(s);
    return fmaf(-2.0f, __frcp_rn(e + 1.0f), 1.0f);
}

// full-precision tanh for the node-phase (argument not pre-scaled)
__device__ __forceinline__ float fast_tanh(float x) {
    float e = __expf(2.0f * x);
    return 1.0f - 2.0f * __fdividef(1.0f, e + 1.0f);
}

// ---- Pass 1: x->fp16 pack (grid-stride prologue) + scatter (rl,col) into bins ----
__global__ __launch_bounds__(1024) void bin_scatter_k(
    const int* __restrict__ row, const int* __restrict__ col,
    const float* __restrict__ x,
    int* __restrict__ binCursor, unsigned int* __restrict__ pack,
    __half* __restrict__ xh)
{
    __shared__ int hist[NB];          // 15.6 KB -> 2 blocks/CU
    // x -> fp16x4 pack (independent of the edge phase; consumed by bucket_agg)
    for (int i = blockIdx.x * 1024 + threadIdx.x; i < NN; i += BIN_BLOCKS * 1024) {
        union { __half2 h2[2]; uint2 u; } o;
        o.h2[0] = __floats2half2_rn(x[3 * i + 0], x[3 * i + 1]);
        o.h2[1] = __floats2half2_rn(x[3 * i + 2], 0.0f);
        *reinterpret_cast<uint2*>(xh + 4 * (size_t)i) = o.u;
    }

    for (int i = threadIdx.x; i < NB; i += 1024) hist[i] = 0;
    __syncthreads();
    int base = blockIdx.x * EPB;

    int r[EPW], c[EPW];
    bool val[EPW];
#pragma unroll
    for (int k = 0; k < EPW; ++k) {
        int e = base + k * 1024 + threadIdx.x;
        val[k] = e < NE;
        r[k] = val[k] ? row[e] : 0;
        c[k] = val[k] ? col[e] : 0;
    }
#pragma unroll
    for (int k = 0; k < EPW; ++k)
        if (val[k]) atomicAdd(&hist[r[k] >> BIN_SH], 1);
    __syncthreads();
    // hist[bin] becomes this block's ABSOLUTE write cursor for that bin
    for (int i = threadIdx.x; i < NB; i += 1024) {
        int cc = hist[i];
        hist[i] = cc ? ((i << CAP_SH) + atomicAdd(&binCursor[i], cc)) : 0;
    }
    __syncthreads();
    int pos[EPW];
#pragma unroll
    for (int k = 0; k < EPW; ++k)
        if (val[k]) pos[k] = atomicAdd(&hist[r[k] >> BIN_SH], 1);   // 16 outstanding
#pragma unroll
    for (int k = 0; k < EPW; ++k)
        if (val[k]) pack[pos[k]] = ((unsigned int)(r[k] & (BIN_SZ - 1)) << 20)
                                   | (unsigned int)c[k];
}

// prefetch one chunk's pack entries + xh gathers into named registers
#define PREFETCH_CHUNK(CS2, GX0, GX1, RL0, RL1)                                   \
    {                                                                             \
        RL0 = RL1 = -1;                                                           \
        int cs2_ = (CS2);                                                         \
        if (cs2_ < ee) {                                                          \
            int mm_ = min(CHUNK, ee - cs2_);                                      \
            int o0_ = tid, o1_ = 256 + tid;                                       \
            if (o0_ < mm_) {                                                      \
                unsigned int p_ = pack[cs2_ + o0_];                               \
                RL0 = (int)(p_ >> 20);                                            \
                GX0 = *reinterpret_cast<const uint2*>(xh + 4 * (size_t)(p_ & 0xFFFFFu)); \
            }                                                                     \
            if (o1_ < mm_) {                                                      \
                unsigned int p_ = pack[cs2_ + o1_];                               \
                RL1 = (int)(p_ >> 20);                                            \
                GX1 = *reinterpret_cast<const uint2*>(xh + 4 * (size_t)(p_ & 0xFFFFFu)); \
            }                                                                     \
        }                                                                         \
    }

// ---- Pass 2: per-bin chunked pipeline, DEPTH-2 software pipeline ----
// Three chunk-stages in flight (A=compute, B=ready, C=issuing): 4 outstanding
// random gathers per thread, each covered by ~2 chunk-phases of compute.
__global__ __launch_bounds__(256) void bucket_agg_k(
    const unsigned int* __restrict__ pack,
    const int* __restrict__ binCursor,   // final per-bin counts
    const __half* __restrict__ xh,  // [NN,4]
    const int* __restrict__ batch,
    const float* __restrict__ w1,   // [3,16]
    const float* __restrict__ b1,   // [16]
    const float* __restrict__ w2,   // [16,16]
    const float* __restrict__ b2,   // [16]
    float* __restrict__ h_sum,      // [NG,16]
    unsigned int* __restrict__ h_max, // [NG,16] monotone-encoded
    int* __restrict__ cnt)          // [NG]
{
    __shared__ uint4 pay[CHUNK * 2];   // 16 KB sorted h1-payloads (16 halfs/edge)
    __shared__ int scnt[BIN_SZ];       // hist -> cursor
    __shared__ int sstart[BIN_SZ];     // exclusive starts
    __shared__ int wsum[4];            // per-wave scan sums

    int tid = threadIdx.x;
    int lane = tid & 63, wid = tid >> 6;
    int b = blockIdx.x;
    int nodeBase = b << BIN_SH;
    int nNodes = min(BIN_SZ, NN - nodeBase);   // 256, or 64 for last bin (%64==0)
    int es = b << CAP_SH;
    int ee = es + binCursor[b];

    // one-time: bias pre-scaled by KEXP (16 VGPR)
    float b1s[16];
#pragma unroll
    for (int j = 0; j < 16; ++j) b1s[j] = b1[j] * KEXP;

    __half2 acc8[8];
#pragma unroll
    for (int q = 0; q < 8; ++q) acc8[q] = __half2half2(__float2half(0.0f));
    int dg = 0;

    // prefetch chunks 0 and 1 (A oldest -> waits on A leave B/C in flight)
    uint2 gxA0, gxA1, gxB0, gxB1;
    int rlA0, rlA1, rlB0, rlB1;
    PREFETCH_CHUNK(es,          gxA0, gxA1, rlA0, rlA1);
    PREFETCH_CHUNK(es + CHUNK,  gxB0, gxB1, rlB0, rlB1);

    for (int cs = es; cs < ee; cs += CHUNK) {
        int m = min(CHUNK, ee - cs);
        scnt[tid] = 0;
        __syncthreads();                                   // B1

        // histogram current chunk from prefetched rl
        if (rlA0 >= 0) atomicAdd(&scnt[rlA0], 1);          // no-return ds_add
        if (rlA1 >= 0) atomicAdd(&scnt[rlA1], 1);

        // issue chunk i+2 prefetch NOW: spans this whole iteration
        uint2 gxC0, gxC1;
        int rlC0, rlC1;
        PREFETCH_CHUNK(cs + 2 * CHUNK, gxC0, gxC1, rlC0, rlC1);
        __syncthreads();                                   // B2

        // exclusive scan of scnt via wave shuffles
        int v = scnt[tid];
        int sc = v;
#pragma unroll
        for (int off = 1; off < 64; off <<= 1) {
            int u = __shfl_up(sc, off);
            if (lane >= off) sc += u;
        }
        if (lane == 63) wsum[wid] = sc;
        __syncthreads();                                   // B3
        int pre = 0;
#pragma unroll
        for (int w = 0; w < 4; ++w) pre += (w < wid) ? wsum[w] : 0;
        int ex = pre + sc - v;
        sstart[tid] = ex;
        scnt[tid] = ex;
        __syncthreads();                                   // B4

        // EDGE-PARALLEL MLP1 + tanh (pre-scaled args), then counting-sort scatter
#pragma unroll
        for (int k = 0; k < 2; ++k) {
            int rlk = k ? rlA1 : rlA0;
            if (rlk >= 0) {
                union { uint2 u; __half2 h2[2]; } xi;
                xi.u = k ? gxA1 : gxA0;
                float2 x01 = __half22float2(xi.h2[0]);
                float xs0 = x01.x * KEXP;
                float xs1 = x01.y * KEXP;
                float xs2 = __low2float(xi.h2[1]) * KEXP;
                union { __half2 h2[8]; uint4 u[2]; } o;
#pragma unroll
                for (int q = 0; q < 8; ++q) {
                    float va = fmaf(xs2, w1[32 + 2 * q], fmaf(xs1, w1[16 + 2 * q],
                               fmaf(xs0, w1[2 * q], b1s[2 * q])));
                    float vb = fmaf(xs2, w1[33 + 2 * q], fmaf(xs1, w1[17 + 2 * q],
                               fmaf(xs0, w1[2 * q + 1], b1s[2 * q + 1])));
                    o.h2[q] = __floats2half2_rn(tanh_scaled(va), tanh_scaled(vb));
                }
                int pos = atomicAdd(&scnt[rlk], 1);   // returning ds_add_rtn
                pay[2 * pos + 0] = o.u[0];
                pay[2 * pos + 1] = o.u[1];
            }
        }
        __syncthreads();                                   // B5

        // owner accumulation: thread tid owns node tid; 8 pk_add_f16 per edge
        if (tid < nNodes) {
            int s0 = sstart[tid];
            int e0 = (tid < 255) ? sstart[tid + 1] : m;
            dg += e0 - s0;
            for (int e = s0; e < e0; ++e) {
                union { uint4 u; __half2 h2[4]; } ua, ub;
                ua.u = pay[2 * e + 0];
                ub.u = pay[2 * e + 1];
#pragma unroll
                for (int q = 0; q < 4; ++q) {
                    acc8[q] = __hadd2(acc8[q], ua.h2[q]);
                    acc8[4 + q] = __hadd2(acc8[4 + q], ub.h2[q]);
                }
            }
        }
        __syncthreads();                                   // B6

        // rotate pipeline: A <- B <- C
        gxA0 = gxB0; gxA1 = gxB1; rlA0 = rlB0; rlA1 = rlB1;
        gxB0 = gxC0; gxB1 = gxC1; rlB0 = rlC0; rlB1 = rlC1;
    }

    // node phase: normalize, MLP2, tanh, segmented wave reduction over sorted batch
    if (tid < nNodes) {                       // wave-uniform (nNodes % 64 == 0)
        float acc[16];
#pragma unroll
        for (int q = 0; q < 8; ++q) {
            float2 f = __half22float2(acc8[q]);
            acc[2 * q + 0] = f.x;
            acc[2 * q + 1] = f.y;
        }
        float inv = 1.0f / fmaxf((float)dg, 1.0f);
        float s[16];
#pragma unroll
        for (int j = 0; j < 16; ++j) s[j] = b2[j];
#pragma unroll
        for (int k = 0; k < 16; ++k) {
            float a = acc[k] * inv;
#pragma unroll
            for (int j = 0; j < 16; ++j) s[j] = fmaf(a, w2[16 * k + j], s[j]);
        }
        float m[16];
#pragma unroll
        for (int j = 0; j < 16; ++j) { s[j] = fast_tanh(s[j]); m[j] = s[j]; }

        int g = batch[nodeBase + tid];
        int gp = __shfl_up(g, 1);
        int head = (lane == 0) || (g != gp);
        unsigned long long hm = __ballot(head != 0);

        int f = head;
#pragma unroll
        for (int off = 1; off < 64; off <<= 1) {
            int fu = __shfl_up(f, off);
            bool take = (lane >= off) && (f == 0);
#pragma unroll
            for (int j = 0; j < 16; ++j) {
                float su = __shfl_up(s[j], off);
                float mu = __shfl_up(m[j], off);
                if (take) { s[j] += su; m[j] = fmaxf(m[j], mu); }
            }
            if (lane >= off) f |= fu;
        }

        int hnext = __shfl_down(head, 1);
        bool is_last = (lane == 63) || (hnext != 0);
        if (is_last) {
            unsigned long long below = hm & (~0ULL >> (63 - lane));
            int start = 63 - __clzll(below);
            int seglen = lane - start + 1;
#pragma unroll
            for (int j = 0; j < 16; ++j) {
                unsafeAtomicAdd(&h_sum[16 * g + j], s[j]);
                atomicMax(&h_max[16 * g + j], __float_as_uint(m[j] + 2.0f));
            }
            atomicAdd(&cnt[g], seglen);
        }
    }
}

// ---- Pass 3: head ----
__global__ __launch_bounds__(256) void out_k(
    const float* __restrict__ h_sum,
    const unsigned int* __restrict__ h_max,
    const int* __restrict__ cnt,
    const float* __restrict__ w3,   // [32]
    const float* __restrict__ b3,   // [1]
    float* __restrict__ out)        // [NG]
{
    int g = blockIdx.x * 256 + threadIdx.x;
    if (g >= NG) return;
    float invc = 1.0f / fmaxf((float)cnt[g], 1.0f);
    float acc = b3[0];
#pragma unroll
    for (int j = 0; j < 16; ++j) {
        float mean = h_sum[16 * g + j] * invc;
        unsigned int e = h_max[16 * g + j];
        float mx = (e == 0u) ? 0.0f : (__uint_as_float(e) - 2.0f);
        acc = fmaf(mean, w3[j], fmaf(mx, w3[16 + j], acc));
    }
    out[g] = 1.0f / (1.0f + __expf(-acc));
}

extern "C" void kernel_launch(void* const* d_in, const int* in_sizes, int n_in,
                              void* d_out, int out_size, void* d_ws, size_t ws_size,
                              hipStream_t stream)
{
    const float* x   = (const float*)d_in[0];
    const int*   ei  = (const int*)d_in[1];   // row = ei, col = ei + NE
    const int*   bat = (const int*)d_in[2];
    const float* w1  = (const float*)d_in[3];
    const float* b1  = (const float*)d_in[4];
    const float* w2  = (const float*)d_in[5];
    const float* b2  = (const float*)d_in[6];
    const float* w3  = (const float*)d_in[7];
    const float* b3  = (const float*)d_in[8];
    float* out = (float*)d_out;

    char* ws = (char*)d_ws;
    size_t off = 0;
    // --- zeroed region (one small memset, ~0.57 MB) ---
    int* binCursor = (int*)(ws + off);         off += 16384;                 // NB ints, padded
    float* h_sum  = (float*)(ws + off);        off += (size_t)NG * 16 * 4;
    unsigned int* h_max = (unsigned int*)(ws + off); off += (size_t)NG * 16 * 4;
    int* cnt      = (int*)(ws + off);          off += (size_t)NG * 4;
    size_t zero_bytes = off;
    // --- non-zeroed scratch (total ~41 MB) ---
    unsigned int* pack = (unsigned int*)(ws + off); off += (size_t)NB * CAP * 4; // 32 MB
    __half* xh    = (__half*)(ws + off);       off += (size_t)NN * 4 * 2;    // 8 MB

    hipMemsetAsync(d_ws, 0, zero_bytes, stream);

    bin_scatter_k<<<BIN_BLOCKS, 1024, 0, stream>>>(ei, ei + NE, x, binCursor, pack, xh);
    bucket_agg_k<<<NB, 256, 0, stream>>>(pack, binCursor, xh, bat,
                                         w1, b1, w2, b2, h_sum, h_max, cnt);
    out_k<<<(NG + 255) / 256, 256, 0, stream>>>(h_sum, h_max, cnt, w3, b3, out);
}

// Round 19
// 185.647 us; speedup vs baseline: 1.0099x; 1.0099x over previous
//
#include <hip/hip_runtime.h>
#include <hip/hip_bf16.h>
#include <hip/hip_fp16.h>

static constexpr int NN = 1000000;   // nodes
static constexpr int NE = 5000000;   // edges
static constexpr int NG = 4096;      // graphs
static constexpr int BIN_SH = 8;                      // 256 nodes per bin
static constexpr int BIN_SZ = 1 << BIN_SH;            // 256
static constexpr int NB = (NN + BIN_SZ - 1) >> BIN_SH;   // 3907 (last bin = 64 nodes, %64==0)
static constexpr int CAP_SH = 11;                     // 2048 edge slots per bin
static constexpr int CAP = 1 << CAP_SH;
static constexpr int EPB = 16384;                     // edges per block for the scatter pass
static constexpr int EPW = EPB / 1024;                // 16 edges per thread in scatter
static constexpr int BIN_BLOCKS = (NE + EPB - 1) / EPB;  // 306 (1024-thread blocks)
static constexpr int CHUNK = 512;                     // edges per LDS chunk (18 KB -> 8 blocks/CU)
static constexpr float KEXP = 2.8853900817779268f;    // 2*log2(e): tanh(v)=1-2/(2^(K v)+1)

__device__ __forceinline__ float exp2_fast(float x) {
#if __has_builtin(__builtin_amdgcn_exp2f)
    return __builtin_amdgcn_exp2f(x);
#else
    return exp2f(x);
#endif
}

// tanh from pre-scaled argument s = KEXP * v: tanh(v) = 1 - 2/(2^s + 1).
__device__ __forceinline__ float tanh_scaled(float s) {
    float e = exp2_fast(s);
    return fmaf(-2.0f, __frcp_rn(e + 1.0f), 1.0f);
}

// full-precision tanh for the node-phase (argument not pre-scaled)
__device__ __forceinline__ float fast_tanh(float x) {
    float e = __expf(2.0f * x);
    return 1.0f - 2.0f * __fdividef(1.0f, e + 1.0f);
}

// LDS-only barrier: waits LDS ops (lgkmcnt) but lets GLOBAL loads (vmcnt)
// stay in flight across the barrier. __syncthreads() would emit
// s_waitcnt vmcnt(0) and drain every prefetched gather (the round-16..18
// pipeline nulls). All barriers in bucket_agg protect LDS only.
__device__ __forceinline__ void lds_barrier() {
    __builtin_amdgcn_sched_barrier(0);
    asm volatile("s_waitcnt lgkmcnt(0)" ::: "memory");
    __builtin_amdgcn_s_barrier();
    __builtin_amdgcn_sched_barrier(0);
}

// ---- Pass 1: x->fp16 pack (grid-stride prologue) + scatter (rl,col) into bins ----
__global__ __launch_bounds__(1024) void bin_scatter_k(
    const int* __restrict__ row, const int* __restrict__ col,
    const float* __restrict__ x,
    int* __restrict__ binCursor, unsigned int* __restrict__ pack,
    __half* __restrict__ xh)
{
    __shared__ int hist[NB];          // 15.6 KB -> 2 blocks/CU
    // x -> fp16x4 pack (independent of the edge phase; consumed by bucket_agg)
    for (int i = blockIdx.x * 1024 + threadIdx.x; i < NN; i += BIN_BLOCKS * 1024) {
        union { __half2 h2[2]; uint2 u; } o;
        o.h2[0] = __floats2half2_rn(x[3 * i + 0], x[3 * i + 1]);
        o.h2[1] = __floats2half2_rn(x[3 * i + 2], 0.0f);
        *reinterpret_cast<uint2*>(xh + 4 * (size_t)i) = o.u;
    }

    for (int i = threadIdx.x; i < NB; i += 1024) hist[i] = 0;
    __syncthreads();
    int base = blockIdx.x * EPB;

    int r[EPW], c[EPW];
    bool val[EPW];
#pragma unroll
    for (int k = 0; k < EPW; ++k) {
        int e = base + k * 1024 + threadIdx.x;
        val[k] = e < NE;
        r[k] = val[k] ? row[e] : 0;
        c[k] = val[k] ? col[e] : 0;
    }
#pragma unroll
    for (int k = 0; k < EPW; ++k)
        if (val[k]) atomicAdd(&hist[r[k] >> BIN_SH], 1);
    __syncthreads();
    // hist[bin] becomes this block's ABSOLUTE write cursor for that bin
    for (int i = threadIdx.x; i < NB; i += 1024) {
        int cc = hist[i];
        hist[i] = cc ? ((i << CAP_SH) + atomicAdd(&binCursor[i], cc)) : 0;
    }
    __syncthreads();
    int pos[EPW];
#pragma unroll
    for (int k = 0; k < EPW; ++k)
        if (val[k]) pos[k] = atomicAdd(&hist[r[k] >> BIN_SH], 1);   // 16 outstanding
#pragma unroll
    for (int k = 0; k < EPW; ++k)
        if (val[k]) pack[pos[k]] = ((unsigned int)(r[k] & (BIN_SZ - 1)) << 20)
                                   | (unsigned int)c[k];
}

// prefetch one chunk's pack entries + xh gathers into named registers
#define PREFETCH_CHUNK(CS2, GX0, GX1, RL0, RL1)                                   \
    {                                                                             \
        RL0 = RL1 = -1;                                                           \
        int cs2_ = (CS2);                                                         \
        if (cs2_ < ee) {                                                          \
            int mm_ = min(CHUNK, ee - cs2_);                                      \
            int o0_ = tid, o1_ = 256 + tid;                                       \
            if (o0_ < mm_) {                                                      \
                unsigned int p_ = pack[cs2_ + o0_];                               \
                RL0 = (int)(p_ >> 20);                                            \
                GX0 = *reinterpret_cast<const uint2*>(xh + 4 * (size_t)(p_ & 0xFFFFFu)); \
            }                                                                     \
            if (o1_ < mm_) {                                                      \
                unsigned int p_ = pack[cs2_ + o1_];                               \
                RL1 = (int)(p_ >> 20);                                            \
                GX1 = *reinterpret_cast<const uint2*>(xh + 4 * (size_t)(p_ & 0xFFFFFu)); \
            }                                                                     \
        }                                                                         \
    }

// ---- Pass 2: per-bin chunked pipeline, depth-2 + LDS-only barriers ----
// With vmcnt no longer drained at barriers, the depth-2 prefetch gives each
// random xh-gather ~2 full chunks of compute cover.
__global__ __launch_bounds__(256) void bucket_agg_k(
    const unsigned int* __restrict__ pack,
    const int* __restrict__ binCursor,   // final per-bin counts
    const __half* __restrict__ xh,  // [NN,4]
    const int* __restrict__ batch,
    const float* __restrict__ w1,   // [3,16]
    const float* __restrict__ b1,   // [16]
    const float* __restrict__ w2,   // [16,16]
    const float* __restrict__ b2,   // [16]
    float* __restrict__ h_sum,      // [NG,16]
    unsigned int* __restrict__ h_max, // [NG,16] monotone-encoded
    int* __restrict__ cnt)          // [NG]
{
    __shared__ uint4 pay[CHUNK * 2];   // 16 KB sorted h1-payloads (16 halfs/edge)
    __shared__ int scnt[BIN_SZ];       // hist -> cursor
    __shared__ int sstart[BIN_SZ];     // exclusive starts
    __shared__ int wsum[4];            // per-wave scan sums

    int tid = threadIdx.x;
    int lane = tid & 63, wid = tid >> 6;
    int b = blockIdx.x;
    int nodeBase = b << BIN_SH;
    int nNodes = min(BIN_SZ, NN - nodeBase);   // 256, or 64 for last bin (%64==0)
    int es = b << CAP_SH;
    int ee = es + binCursor[b];

    // one-time: bias pre-scaled by KEXP (16 VGPR)
    float b1s[16];
#pragma unroll
    for (int j = 0; j < 16; ++j) b1s[j] = b1[j] * KEXP;

    __half2 acc8[8];
#pragma unroll
    for (int q = 0; q < 8; ++q) acc8[q] = __half2half2(__float2half(0.0f));
    int dg = 0;

    // prefetch chunks 0 and 1 (A oldest; consumed first)
    uint2 gxA0, gxA1, gxB0, gxB1;
    int rlA0, rlA1, rlB0, rlB1;
    PREFETCH_CHUNK(es,          gxA0, gxA1, rlA0, rlA1);
    PREFETCH_CHUNK(es + CHUNK,  gxB0, gxB1, rlB0, rlB1);

    for (int cs = es; cs < ee; cs += CHUNK) {
        int m = min(CHUNK, ee - cs);
        scnt[tid] = 0;
        lds_barrier();                                     // B1 (LDS only)

        // histogram current chunk from prefetched rl
        if (rlA0 >= 0) atomicAdd(&scnt[rlA0], 1);          // no-return ds_add
        if (rlA1 >= 0) atomicAdd(&scnt[rlA1], 1);

        // issue chunk i+2 prefetch: stays in flight across ALL barriers below
        uint2 gxC0, gxC1;
        int rlC0, rlC1;
        PREFETCH_CHUNK(cs + 2 * CHUNK, gxC0, gxC1, rlC0, rlC1);
        lds_barrier();                                     // B2

        // exclusive scan of scnt via wave shuffles
        int v = scnt[tid];
        int sc = v;
#pragma unroll
        for (int off = 1; off < 64; off <<= 1) {
            int u = __shfl_up(sc, off);
            if (lane >= off) sc += u;
        }
        if (lane == 63) wsum[wid] = sc;
        lds_barrier();                                     // B3
        int pre = 0;
#pragma unroll
        for (int w = 0; w < 4; ++w) pre += (w < wid) ? wsum[w] : 0;
        int ex = pre + sc - v;
        sstart[tid] = ex;
        scnt[tid] = ex;
        lds_barrier();                                     // B4

        // EDGE-PARALLEL MLP1 + tanh (pre-scaled args), then counting-sort scatter
#pragma unroll
        for (int k = 0; k < 2; ++k) {
            int rlk = k ? rlA1 : rlA0;
            if (rlk >= 0) {
                union { uint2 u; __half2 h2[2]; } xi;
                xi.u = k ? gxA1 : gxA0;
                float2 x01 = __half22float2(xi.h2[0]);
                float xs0 = x01.x * KEXP;
                float xs1 = x01.y * KEXP;
                float xs2 = __low2float(xi.h2[1]) * KEXP;
                union { __half2 h2[8]; uint4 u[2]; } o;
#pragma unroll
                for (int q = 0; q < 8; ++q) {
                    float va = fmaf(xs2, w1[32 + 2 * q], fmaf(xs1, w1[16 + 2 * q],
                               fmaf(xs0, w1[2 * q], b1s[2 * q])));
                    float vb = fmaf(xs2, w1[33 + 2 * q], fmaf(xs1, w1[17 + 2 * q],
                               fmaf(xs0, w1[2 * q + 1], b1s[2 * q + 1])));
                    o.h2[q] = __floats2half2_rn(tanh_scaled(va), tanh_scaled(vb));
                }
                int pos = atomicAdd(&scnt[rlk], 1);   // returning ds_add_rtn
                pay[2 * pos + 0] = o.u[0];
                pay[2 * pos + 1] = o.u[1];
            }
        }
        lds_barrier();                                     // B5

        // owner accumulation: thread tid owns node tid; 8 pk_add_f16 per edge
        if (tid < nNodes) {
            int s0 = sstart[tid];
            int e0 = (tid < 255) ? sstart[tid + 1] : m;
            dg += e0 - s0;
            for (int e = s0; e < e0; ++e) {
                union { uint4 u; __half2 h2[4]; } ua, ub;
                ua.u = pay[2 * e + 0];
                ub.u = pay[2 * e + 1];
#pragma unroll
                for (int q = 0; q < 4; ++q) {
                    acc8[q] = __hadd2(acc8[q], ua.h2[q]);
                    acc8[4 + q] = __hadd2(acc8[4 + q], ub.h2[q]);
                }
            }
        }
        lds_barrier();                                     // B6

        // rotate pipeline: A <- B <- C
        gxA0 = gxB0; gxA1 = gxB1; rlA0 = rlB0; rlA1 = rlB1;
        gxB0 = gxC0; gxB1 = gxC1; rlB0 = rlC0; rlB1 = rlC1;
    }

    // node phase: normalize, MLP2, tanh, segmented wave reduction over sorted batch
    if (tid < nNodes) {                       // wave-uniform (nNodes % 64 == 0)
        float acc[16];
#pragma unroll
        for (int q = 0; q < 8; ++q) {
            float2 f = __half22float2(acc8[q]);
            acc[2 * q + 0] = f.x;
            acc[2 * q + 1] = f.y;
        }
        float inv = 1.0f / fmaxf((float)dg, 1.0f);
        float s[16];
#pragma unroll
        for (int j = 0; j < 16; ++j) s[j] = b2[j];
#pragma unroll
        for (int k = 0; k < 16; ++k) {
            float a = acc[k] * inv;
#pragma unroll
            for (int j = 0; j < 16; ++j) s[j] = fmaf(a, w2[16 * k + j], s[j]);
        }
        float m[16];
#pragma unroll
        for (int j = 0; j < 16; ++j) { s[j] = fast_tanh(s[j]); m[j] = s[j]; }

        int g = batch[nodeBase + tid];
        int gp = __shfl_up(g, 1);
        int head = (lane == 0) || (g != gp);
        unsigned long long hm = __ballot(head != 0);

        int f = head;
#pragma unroll
        for (int off = 1; off < 64; off <<= 1) {
            int fu = __shfl_up(f, off);
            bool take = (lane >= off) && (f == 0);
#pragma unroll
            for (int j = 0; j < 16; ++j) {
                float su = __shfl_up(s[j], off);
                float mu = __shfl_up(m[j], off);
                if (take) { s[j] += su; m[j] = fmaxf(m[j], mu); }
            }
            if (lane >= off) f |= fu;
        }

        int hnext = __shfl_down(head, 1);
        bool is_last = (lane == 63) || (hnext != 0);
        if (is_last) {
            unsigned long long below = hm & (~0ULL >> (63 - lane));
            int start = 63 - __clzll(below);
            int seglen = lane - start + 1;
#pragma unroll
            for (int j = 0; j < 16; ++j) {
                unsafeAtomicAdd(&h_sum[16 * g + j], s[j]);
                atomicMax(&h_max[16 * g + j], __float_as_uint(m[j] + 2.0f));
            }
            atomicAdd(&cnt[g], seglen);
        }
    }
}

// ---- Pass 3: head ----
__global__ __launch_bounds__(256) void out_k(
    const float* __restrict__ h_sum,
    const unsigned int* __restrict__ h_max,
    const int* __restrict__ cnt,
    const float* __restrict__ w3,   // [32]
    const float* __restrict__ b3,   // [1]
    float* __restrict__ out)        // [NG]
{
    int g = blockIdx.x * 256 + threadIdx.x;
    if (g >= NG) return;
    float invc = 1.0f / fmaxf((float)cnt[g], 1.0f);
    float acc = b3[0];
#pragma unroll
    for (int j = 0; j < 16; ++j) {
        float mean = h_sum[16 * g + j] * invc;
        unsigned int e = h_max[16 * g + j];
        float mx = (e == 0u) ? 0.0f : (__uint_as_float(e) - 2.0f);
        acc = fmaf(mean, w3[j], fmaf(mx, w3[16 + j], acc));
    }
    out[g] = 1.0f / (1.0f + __expf(-acc));
}

extern "C" void kernel_launch(void* const* d_in, const int* in_sizes, int n_in,
                              void* d_out, int out_size, void* d_ws, size_t ws_size,
                              hipStream_t stream)
{
    const float* x   = (const float*)d_in[0];
    const int*   ei  = (const int*)d_in[1];   // row = ei, col = ei + NE
    const int*   bat = (const int*)d_in[2];
    const float* w1  = (const float*)d_in[3];
    const float* b1  = (const float*)d_in[4];
    const float* w2  = (const float*)d_in[5];
    const float* b2  = (const float*)d_in[6];
    const float* w3  = (const float*)d_in[7];
    const float* b3  = (const float*)d_in[8];
    float* out = (float*)d_out;

    char* ws = (char*)d_ws;
    size_t off = 0;
    // --- zeroed region (one small memset, ~0.57 MB) ---
    int* binCursor = (int*)(ws + off);         off += 16384;                 // NB ints, padded
    float* h_sum  = (float*)(ws + off);        off += (size_t)NG * 16 * 4;
    unsigned int* h_max = (unsigned int*)(ws + off); off += (size_t)NG * 16 * 4;
    int* cnt      = (int*)(ws + off);          off += (size_t)NG * 4;
    size_t zero_bytes = off;
    // --- non-zeroed scratch (total ~41 MB) ---
    unsigned int* pack = (unsigned int*)(ws + off); off += (size_t)NB * CAP * 4; // 32 MB
    __half* xh    = (__half*)(ws + off);       off += (size_t)NN * 4 * 2;    // 8 MB

    hipMemsetAsync(d_ws, 0, zero_bytes, stream);

    bin_scatter_k<<<BIN_BLOCKS, 1024, 0, stream>>>(ei, ei + NE, x, binCursor, pack, xh);
    bucket_agg_k<<<NB, 256, 0, stream>>>(pack, binCursor, xh, bat,
                                         w1, b1, w2, b2, h_sum, h_max, cnt);
    out_k<<<(NG + 255) / 256, 256, 0, stream>>>(h_sum, h_max, cnt, w3, b3, out);
}